// Round 8
// baseline (405.717 us; speedup 1.0000x reference)
//
#include <hip/hip_runtime.h>

#define L_ 4096
#define D_ 1536
#define NH 12
#define HD 128

typedef __attribute__((ext_vector_type(8))) __bf16 bf16x8;
typedef __attribute__((ext_vector_type(8))) unsigned short ushort8v;
typedef __attribute__((ext_vector_type(4))) float floatx4;

#if __has_builtin(__builtin_amdgcn_exp2f)
#define EXP2F(x) __builtin_amdgcn_exp2f(x)
#else
#define EXP2F(x) exp2f(x)
#endif

__device__ __forceinline__ unsigned short f2bf(float f) {
  union { float f; unsigned int u; } v; v.f = f;
  unsigned int u = v.u;
  return (unsigned short)((u + 0x7fffu + ((u >> 16) & 1u)) >> 16);
}
__device__ __forceinline__ float bf2f(unsigned short h) {
  union { unsigned int u; float f; } v; v.u = ((unsigned int)h) << 16;
  return v.f;
}

// ---------------- fp32 -> bf16 conversion ----------------
__device__ __forceinline__ void cvt8(const float* __restrict__ in,
                                     unsigned short* __restrict__ out, int i) {
  const float4* p = (const float4*)(in + (size_t)i * 8);
  float4 a = p[0], b = p[1];
  ushort8v o;
  o[0] = f2bf(a.x); o[1] = f2bf(a.y); o[2] = f2bf(a.z); o[3] = f2bf(a.w);
  o[4] = f2bf(b.x); o[5] = f2bf(b.y); o[6] = f2bf(b.z); o[7] = f2bf(b.w);
  *(ushort8v*)(out + (size_t)i * 8) = o;
}

__global__ __launch_bounds__(256) void cvt_f32_bf16(const float* __restrict__ in,
                                                    unsigned short* __restrict__ out,
                                                    int n8) {
  int i = blockIdx.x * 256 + threadIdx.x;
  if (i >= n8) return;
  cvt8(in, out, i);
}

// One dispatch converting x + Wq + Wk + Wv + Wo. Grid exactly covers all.
__global__ __launch_bounds__(256) void cvt_all(const float* __restrict__ x,
                                               const float* __restrict__ wq,
                                               const float* __restrict__ wk,
                                               const float* __restrict__ wv,
                                               const float* __restrict__ wo,
                                               unsigned short* __restrict__ xb,
                                               unsigned short* __restrict__ b0,
                                               unsigned short* __restrict__ b1,
                                               unsigned short* __restrict__ b2,
                                               unsigned short* __restrict__ b3) {
  const int NX = L_ * D_ / 8, NW = D_ * D_ / 8;
  int i = blockIdx.x * 256 + threadIdx.x;
  if (i < NX)               { cvt8(x,  xb, i); }
  else if (i < NX + NW)     { cvt8(wq, b0, i - NX); }
  else if (i < NX + 2 * NW) { cvt8(wk, b1, i - NX - NW); }
  else if (i < NX + 3 * NW) { cvt8(wv, b2, i - NX - 2 * NW); }
  else                      { cvt8(wo, b3, i - NX - 3 * NW); }
}

// ---------------- GEMM core (m97 structure) ----------------
template <int MODE>
__device__ __forceinline__ void gemm_core(const unsigned short* __restrict__ A,
                                          const unsigned short* __restrict__ Bw,
                                          const float* __restrict__ bias,
                                          void* __restrict__ Cout,
                                          int M, int Nn, int K,
                                          int m0, int n0,
                                          unsigned short* As, unsigned short* Bs) {
  int t = threadIdx.x;
  int lane = t & 63, wv = t >> 6;
  int wm = (wv & 1) * 64, wn = (wv >> 1) * 64;
  floatx4 zero = {0.f, 0.f, 0.f, 0.f};
  floatx4 acc[4][4];
#pragma unroll
  for (int i = 0; i < 4; ++i)
#pragma unroll
    for (int j = 0; j < 4; ++j) acc[i][j] = zero;
  int fm = lane & 15, fk = (lane >> 4) * 8;

  for (int kt = 0; kt < K; kt += 32) {
    __syncthreads();
#pragma unroll
    for (int it = 0; it < 2; ++it) {
      int c = it * 256 + t;
      int row = c >> 2, col = (c & 3) * 8;
      const unsigned short* ga = A + (size_t)(m0 + row) * K + kt + col;
      const unsigned short* gb = Bw + (size_t)(n0 + row) * K + kt + col;
      __builtin_amdgcn_global_load_lds(
          (const __attribute__((address_space(1))) void*)ga,
          (__attribute__((address_space(3))) void*)((char*)As + (it * 256 + wv * 64) * 16),
          16, 0, 0);
      __builtin_amdgcn_global_load_lds(
          (const __attribute__((address_space(1))) void*)gb,
          (__attribute__((address_space(3))) void*)((char*)Bs + (it * 256 + wv * 64) * 16),
          16, 0, 0);
    }
    __syncthreads();
    bf16x8 af[4], bfr[4];
#pragma unroll
    for (int i = 0; i < 4; ++i) {
      af[i]  = *(const bf16x8*)&As[(wm + 16 * i + fm) * 32 + fk];
      bfr[i] = *(const bf16x8*)&Bs[(wn + 16 * i + fm) * 32 + fk];
    }
#pragma unroll
    for (int i = 0; i < 4; ++i)
#pragma unroll
      for (int j = 0; j < 4; ++j)
        acc[i][j] = __builtin_amdgcn_mfma_f32_16x16x32_bf16(af[i], bfr[j], acc[i][j], 0, 0, 0);
  }

  int fr = (lane >> 4) * 4;
#pragma unroll
  for (int j = 0; j < 4; ++j) {
    int col = n0 + wn + 16 * j + fm;
    float bz = bias[col];
#pragma unroll
    for (int i = 0; i < 4; ++i) {
      int row0 = m0 + wm + 16 * i + fr;
      if (MODE == 2) {
        ushort4 pk = make_ushort4(f2bf(acc[i][j][0] + bz), f2bf(acc[i][j][1] + bz),
                                  f2bf(acc[i][j][2] + bz), f2bf(acc[i][j][3] + bz));
        size_t off = (size_t)(row0 >> 5) * Nn * 32 + (size_t)col * 32 + (row0 & 31);
        *(ushort4*)&((unsigned short*)Cout)[off] = pk;
      } else {
#pragma unroll
        for (int r = 0; r < 4; ++r) {
          float val = acc[i][j][r] + bz;
          if (MODE == 1) ((unsigned short*)Cout)[(size_t)(row0 + r) * Nn + col] = f2bf(val);
          else           ((float*)Cout)[(size_t)(row0 + r) * Nn + col] = val;
        }
      }
    }
  }
}

template <int MODE>
__global__ __launch_bounds__(256) void gemm_bt(const unsigned short* __restrict__ A,
                                               const unsigned short* __restrict__ Bw,
                                               const float* __restrict__ bias,
                                               void* __restrict__ Cout,
                                               int M, int Nn, int K) {
  __shared__ unsigned short As[128 * 32];
  __shared__ unsigned short Bs[128 * 32];
  gemm_core<MODE>(A, Bw, bias, Cout, M, Nn, K, blockIdx.y * 128, blockIdx.x * 128, As, Bs);
}

// Fused QKV: one dispatch, 1152 blocks.
__global__ __launch_bounds__(256) void gemm_qkv(const unsigned short* __restrict__ xb,
                                                const unsigned short* __restrict__ wq,
                                                const unsigned short* __restrict__ wk,
                                                const unsigned short* __restrict__ wv,
                                                const float* __restrict__ bq,
                                                const float* __restrict__ bk,
                                                const float* __restrict__ bv,
                                                unsigned short* __restrict__ outq,
                                                unsigned short* __restrict__ outk,
                                                unsigned short* __restrict__ outv) {
  __shared__ unsigned short As[128 * 32];
  __shared__ unsigned short Bs[128 * 32];
  int which = blockIdx.x / (D_ / 128);
  int n0 = (blockIdx.x % (D_ / 128)) * 128;
  int m0 = blockIdx.y * 128;
  if (which == 0)
    gemm_core<1>(xb, wq, bq, outq, L_, D_, D_, m0, n0, As, Bs);
  else if (which == 1)
    gemm_core<1>(xb, wk, bk, outk, L_, D_, D_, m0, n0, As, Bs);
  else
    gemm_core<2>(xb, wv, bv, outv, L_, D_, D_, m0, n0, As, Bs);
}

// ---------------- fused RMSNorm (over D) + 3-axis RoPE, in-place bf16 -------
__global__ __launch_bounds__(256) void rmsrope(unsigned short* __restrict__ qb,
                                               unsigned short* __restrict__ kb,
                                               const float* __restrict__ gq,
                                               const float* __restrict__ gk,
                                               const float* __restrict__ fcos,
                                               const float* __restrict__ fsin,
                                               const int* __restrict__ grid_sizes) {
  int row = blockIdx.x;
  unsigned short* buf = (blockIdx.y == 0) ? qb : kb;
  const float* g = (blockIdx.y == 0) ? gq : gk;
  float osc = (blockIdx.y == 0) ? 0.1275174475f : 1.0f;  // log2(e)/sqrt(128)
  int t = threadIdx.x;
  float xr[3], xi[3];
#pragma unroll
  for (int i = 0; i < 3; ++i) {
    int p = t + i * 256;
    unsigned int raw = *(const unsigned int*)&buf[(size_t)row * D_ + 2 * p];
    xr[i] = bf2f((unsigned short)(raw & 0xffffu));
    xi[i] = bf2f((unsigned short)(raw >> 16));
  }
  float ss = 0.f;
#pragma unroll
  for (int i = 0; i < 3; ++i) ss += xr[i] * xr[i] + xi[i] * xi[i];
  for (int off = 32; off > 0; off >>= 1) ss += __shfl_down(ss, off);
  __shared__ float red[4];
  if ((t & 63) == 0) red[t >> 6] = ss;
  __syncthreads();
  float rs = rsqrtf((red[0] + red[1] + red[2] + red[3]) * (1.0f / D_) + 1e-6f);

  int gf = grid_sizes[0], gh = grid_sizes[1], gw = grid_sizes[2];
  int sl = gf * gh * gw;
  int hw = gh * gw;
  int fi = row / hw, rem = row - fi * hw;
  int hi = rem / gw, wi = rem - hi * gw;
  bool dorope = row < sl;
#pragma unroll
  for (int i = 0; i < 3; ++i) {
    int p = t + i * 256;
    int j = p & 63;
    float a = xr[i] * rs * g[2 * p];
    float b = xi[i] * rs * g[2 * p + 1];
    if (dorope) {
      int pos = (j < 22) ? fi : ((j < 43) ? hi : wi);
      float cs = fcos[pos * 64 + j], sn = fsin[pos * 64 + j];
      float oa = a * cs - b * sn;
      float ob = a * sn + b * cs;
      a = oa; b = ob;
    }
    a *= osc; b *= osc;
    unsigned int packed = (unsigned int)f2bf(a) | ((unsigned int)f2bf(b) << 16);
    *(unsigned int*)&buf[(size_t)row * D_ + 2 * p] = packed;
  }
}

// ---------------- MFMA flash attention: split-K across blocks x NS ----------
// Per-wave structure proven in R7 (VGPR 76, no spill, 0 bank conflicts).
// Grid NS*384 blocks; partial s=0 goes to d_out (fp32 scratch), s>0 into ws.
template <int NS>
__global__ __launch_bounds__(256, 2) void attnS(const unsigned short* __restrict__ Qb,
                                                const unsigned short* __restrict__ Kb,
                                                const unsigned short* __restrict__ Vt,
                                                float* __restrict__ Opd,
                                                float* __restrict__ Opw,
                                                float* __restrict__ lp,
                                                const int* __restrict__ seq_lens) {
  __shared__ unsigned short Ks[2][4096];
  __shared__ unsigned short Vs[2][4096];
  const int KEYS = L_ / NS;
  int t = threadIdx.x, lane = t & 63, w = t >> 6;
  int id = blockIdx.x;
  int u2 = (id & 7) * (NS * 48) + (id >> 3);   // XCD swizzle
  int split = u2 % NS, v = u2 / NS;
  int h = v >> 5, qt = v & 31;
  int q0 = qt * 128 + w * 32;
  int kv0 = split * KEYS;
  float* Opart = (split == 0) ? Opd : (Opw + (size_t)(split - 1) * L_ * D_);
  float* lpart = lp + (size_t)split * L_ * NH;
  int seqlen = seq_lens[0];
  int fl = lane & 15, fg = lane >> 4;

  // Q B-fragments (pre-scaled): B[n=q][k=d]
  bf16x8 qf[2][4];
#pragma unroll
  for (int nj = 0; nj < 2; ++nj)
#pragma unroll
    for (int kd = 0; kd < 4; ++kd)
      qf[nj][kd] = *(const bf16x8*)&Qb[((size_t)(q0 + nj * 16 + fl) * NH + h) * HD + kd * 32 + fg * 8];

  // staging source pointers: K with key permutation; V dest layout [kg][d]
  const unsigned short* kp[2];
  const unsigned short* vp[2];
#pragma unroll
  for (int i = 0; i < 2; ++i) {
    int c = t + i * 256;
    int dgroup = c >> 5, permrow = c & 31;
    int kd = dgroup >> 2, fgc = dgroup & 3, mi = permrow >> 4, flc = permrow & 15;
    int key = (((flc & 12) << 1) | (flc & 3)) + (mi << 2);
    kp[i] = Kb + ((size_t)(kv0 + key) * NH + h) * HD + kd * 32 + fgc * 8;
    int vd = c & 127, vkg = c >> 7;
    vp[i] = Vt + (size_t)(kv0 >> 5) * (D_ * 32) + ((size_t)(h * HD + vd)) * 32 + vkg * 8;
  }
  const int STEP = 32 * NH * HD;

  auto stage = [&](int b) {
#pragma unroll
    for (int i = 0; i < 2; ++i) {
      __builtin_amdgcn_global_load_lds(
          (const __attribute__((address_space(1))) void*)kp[i],
          (__attribute__((address_space(3))) void*)&Ks[b][(i * 256 + w * 64) * 8],
          16, 0, 0);
      __builtin_amdgcn_global_load_lds(
          (const __attribute__((address_space(1))) void*)vp[i],
          (__attribute__((address_space(3))) void*)&Vs[b][(i * 256 + w * 64) * 8],
          16, 0, 0);
      kp[i] += STEP; vp[i] += STEP;
    }
  };

  floatx4 o[2][8];
  floatx4 zero = {0.f, 0.f, 0.f, 0.f};
#pragma unroll
  for (int nj = 0; nj < 2; ++nj)
#pragma unroll
    for (int nt = 0; nt < 8; ++nt) o[nj][nt] = zero;
  float lr[2] = {0.f, 0.f};

  stage(0);
  for (int kt = 0; kt < KEYS; kt += 32) {
    int cur = (kt >> 5) & 1;
    __syncthreads();
    if (kt + 32 < KEYS) stage(cur ^ 1);

    // S^T = K.Q^T
    floatx4 s[2][2];
    s[0][0] = zero; s[0][1] = zero; s[1][0] = zero; s[1][1] = zero;
#pragma unroll
    for (int kd = 0; kd < 4; ++kd)
#pragma unroll
      for (int mi = 0; mi < 2; ++mi) {
        bf16x8 kf = *(const bf16x8*)&Ks[cur][(((kd << 2) | fg) * 32 + (mi << 4) + fl) * 8];
#pragma unroll
        for (int nj = 0; nj < 2; ++nj)
          s[mi][nj] = __builtin_amdgcn_mfma_f32_16x16x32_bf16(kf, qf[nj][kd], s[mi][nj], 0, 0, 0);
      }

    // softmax: raw exp2 (scale pre-folded into Q), deferred l reduction
    bf16x8 pb[2];
    bool full = (kv0 + kt + 32 <= seqlen);
#pragma unroll
    for (int nj = 0; nj < 2; ++nj) {
      float pv[8];
      if (full) {
#pragma unroll
        for (int mi = 0; mi < 2; ++mi)
#pragma unroll
          for (int r = 0; r < 4; ++r) pv[mi * 4 + r] = EXP2F(s[mi][nj][r]);
      } else {
#pragma unroll
        for (int mi = 0; mi < 2; ++mi)
#pragma unroll
          for (int r = 0; r < 4; ++r) {
            int key = kv0 + kt + fg * 8 + mi * 4 + r;
            pv[mi * 4 + r] = (key < seqlen) ? EXP2F(s[mi][nj][r]) : 0.f;
          }
      }
      lr[nj] += ((pv[0] + pv[1]) + (pv[2] + pv[3])) + ((pv[4] + pv[5]) + (pv[6] + pv[7]));
      union { unsigned int u[4]; bf16x8 v; } pk;
#pragma unroll
      for (int jj = 0; jj < 4; ++jj) {
        unsigned int a = __builtin_bit_cast(unsigned int, pv[2 * jj]) + 0x8000u;
        unsigned int b = __builtin_bit_cast(unsigned int, pv[2 * jj + 1]) + 0x8000u;
        pk.u[jj] = (a >> 16) | (b & 0xffff0000u);
      }
      pb[nj] = pk.v;
    }

    // PV: A = pb (registers), B = V d-rows from LDS ([kg][d] layout)
#pragma unroll
    for (int nt = 0; nt < 8; ++nt) {
      bf16x8 vf = *(const bf16x8*)&Vs[cur][((fg << 7) + (nt << 4) + fl) * 8];
#pragma unroll
      for (int nj = 0; nj < 2; ++nj)
        o[nj][nt] = __builtin_amdgcn_mfma_f32_16x16x32_bf16(pb[nj], vf, o[nj][nt], 0, 0, 0);
    }
  }

  // deferred l reduction; write fp32 partials (no normalization here)
#pragma unroll
  for (int nj = 0; nj < 2; ++nj) {
    lr[nj] += __shfl_xor(lr[nj], 16);
    lr[nj] += __shfl_xor(lr[nj], 32);
    int rowb = q0 + nj * 16 + fg * 4;
#pragma unroll
    for (int nt = 0; nt < 8; ++nt) {
      int dcol = h * HD + nt * 16 + fl;
      Opart[(size_t)(rowb + 0) * D_ + dcol] = o[nj][nt][0];
      Opart[(size_t)(rowb + 1) * D_ + dcol] = o[nj][nt][1];
      Opart[(size_t)(rowb + 2) * D_ + dcol] = o[nj][nt][2];
      Opart[(size_t)(rowb + 3) * D_ + dcol] = o[nj][nt][3];
    }
    if (fg == 0) lpart[(size_t)(q0 + nj * 16 + fl) * NH + h] = lr[nj];
  }
}

// combine: out = (sum_s O_s) / (sum_s l_s), bf16
template <int NS>
__global__ __launch_bounds__(256) void attn_combine(const float* __restrict__ Opd,
                                                    const float* __restrict__ Opw,
                                                    const float* __restrict__ lp,
                                                    unsigned short* __restrict__ out) {
  int gid = blockIdx.x * 256 + threadIdx.x;   // over L_*D_/8
  int q = gid / (D_ / 8);
  int col = (gid - q * (D_ / 8)) * 8;
  int h = col >> 7;
  float lsum = 0.f;
#pragma unroll
  for (int s = 0; s < NS; ++s) lsum += lp[(size_t)s * L_ * NH + (size_t)q * NH + h];
  float inv = 1.0f / lsum;
  float acc[8];
  {
    const float4* p = (const float4*)(Opd + (size_t)q * D_ + col);
    float4 a = p[0], b = p[1];
    acc[0] = a.x; acc[1] = a.y; acc[2] = a.z; acc[3] = a.w;
    acc[4] = b.x; acc[5] = b.y; acc[6] = b.z; acc[7] = b.w;
  }
#pragma unroll
  for (int s = 1; s < NS; ++s) {
    const float4* p = (const float4*)(Opw + (size_t)(s - 1) * L_ * D_ + (size_t)q * D_ + col);
    float4 a = p[0], b = p[1];
    acc[0] += a.x; acc[1] += a.y; acc[2] += a.z; acc[3] += a.w;
    acc[4] += b.x; acc[5] += b.y; acc[6] += b.z; acc[7] += b.w;
  }
  ushort8v o;
#pragma unroll
  for (int e = 0; e < 8; ++e) o[e] = f2bf(acc[e] * inv);
  *(ushort8v*)(out + (size_t)q * D_ + col) = o;
}

// ---------------- fallback attention (R5 attn5, bf16 direct out) ------------
__global__ __launch_bounds__(256, 2) void attn5(const unsigned short* __restrict__ Qb,
                                                const unsigned short* __restrict__ Kb,
                                                const unsigned short* __restrict__ Vt,
                                                unsigned short* __restrict__ Ob,
                                                const int* __restrict__ seq_lens) {
  __shared__ unsigned short Ks[2][4096];
  __shared__ unsigned short Vs[2][4096];
  int t = threadIdx.x, lane = t & 63, w = t >> 6;
  int id = blockIdx.x;
  int u = (id & 7) * 48 + (id >> 3);
  int h = u >> 5, qt = u & 31;
  int q0 = qt * 128 + w * 32;
  int seqlen = seq_lens[0];
  int fl = lane & 15, fg = lane >> 4;

  bf16x8 qf[2][4];
#pragma unroll
  for (int nj = 0; nj < 2; ++nj)
#pragma unroll
    for (int kd = 0; kd < 4; ++kd)
      qf[nj][kd] = *(const bf16x8*)&Qb[((size_t)(q0 + nj * 16 + fl) * NH + h) * HD + kd * 32 + fg * 8];

  const unsigned short* kp[2];
  const unsigned short* vp[2];
#pragma unroll
  for (int i = 0; i < 2; ++i) {
    int c = t + i * 256;
    int dgroup = c >> 5, permrow = c & 31;
    int kd = dgroup >> 2, fgc = dgroup & 3, mi = permrow >> 4, flc = permrow & 15;
    int key = (((flc & 12) << 1) | (flc & 3)) + (mi << 2);
    kp[i] = Kb + ((size_t)key * NH + h) * HD + kd * 32 + fgc * 8;
    int vd = c & 127, vkg = c >> 7;
    vp[i] = Vt + ((size_t)(h * HD + vd)) * 32 + vkg * 8;
  }
  const int STEP = 32 * NH * HD;

  auto stage = [&](int b) {
#pragma unroll
    for (int i = 0; i < 2; ++i) {
      __builtin_amdgcn_global_load_lds(
          (const __attribute__((address_space(1))) void*)kp[i],
          (__attribute__((address_space(3))) void*)&Ks[b][(i * 256 + w * 64) * 8],
          16, 0, 0);
      __builtin_amdgcn_global_load_lds(
          (const __attribute__((address_space(1))) void*)vp[i],
          (__attribute__((address_space(3))) void*)&Vs[b][(i * 256 + w * 64) * 8],
          16, 0, 0);
      kp[i] += STEP; vp[i] += STEP;
    }
  };

  floatx4 o[2][8];
  floatx4 zero = {0.f, 0.f, 0.f, 0.f};
#pragma unroll
  for (int nj = 0; nj < 2; ++nj)
#pragma unroll
    for (int nt = 0; nt < 8; ++nt) o[nj][nt] = zero;
  float lr[2] = {0.f, 0.f};

  stage(0);
  for (int kt = 0; kt < L_; kt += 32) {
    int cur = (kt >> 5) & 1;
    __syncthreads();
    if (kt + 32 < L_) stage(cur ^ 1);

    floatx4 s[2][2];
    s[0][0] = zero; s[0][1] = zero; s[1][0] = zero; s[1][1] = zero;
#pragma unroll
    for (int kd = 0; kd < 4; ++kd)
#pragma unroll
      for (int mi = 0; mi < 2; ++mi) {
        bf16x8 kf = *(const bf16x8*)&Ks[cur][(((kd << 2) | fg) * 32 + (mi << 4) + fl) * 8];
#pragma unroll
        for (int nj = 0; nj < 2; ++nj)
          s[mi][nj] = __builtin_amdgcn_mfma_f32_16x16x32_bf16(kf, qf[nj][kd], s[mi][nj], 0, 0, 0);
      }

    bf16x8 pb[2];
    bool full = (kt + 32 <= seqlen);
#pragma unroll
    for (int nj = 0; nj < 2; ++nj) {
      float pv[8];
      if (full) {
#pragma unroll
        for (int mi = 0; mi < 2; ++mi)
#pragma unroll
          for (int r = 0; r < 4; ++r) pv[mi * 4 + r] = EXP2F(s[mi][nj][r]);
      } else {
#pragma unroll
        for (int mi = 0; mi < 2; ++mi)
#pragma unroll
          for (int r = 0; r < 4; ++r) {
            int key = kt + fg * 8 + mi * 4 + r;
            pv[mi * 4 + r] = (key < seqlen) ? EXP2F(s[mi][nj][r]) : 0.f;
          }
      }
      lr[nj] += ((pv[0] + pv[1]) + (pv[2] + pv[3])) + ((pv[4] + pv[5]) + (pv[6] + pv[7]));
      union { unsigned int u[4]; bf16x8 v; } pk;
#pragma unroll
      for (int jj = 0; jj < 4; ++jj) {
        unsigned int a = __builtin_bit_cast(unsigned int, pv[2 * jj]) + 0x8000u;
        unsigned int b = __builtin_bit_cast(unsigned int, pv[2 * jj + 1]) + 0x8000u;
        pk.u[jj] = (a >> 16) | (b & 0xffff0000u);
      }
      pb[nj] = pk.v;
    }

#pragma unroll
    for (int nt = 0; nt < 8; ++nt) {
      bf16x8 vf = *(const bf16x8*)&Vs[cur][((fg << 7) + (nt << 4) + fl) * 8];
#pragma unroll
      for (int nj = 0; nj < 2; ++nj)
        o[nj][nt] = __builtin_amdgcn_mfma_f32_16x16x32_bf16(pb[nj], vf, o[nj][nt], 0, 0, 0);
    }
  }

#pragma unroll
  for (int nj = 0; nj < 2; ++nj) {
    lr[nj] += __shfl_xor(lr[nj], 16);
    lr[nj] += __shfl_xor(lr[nj], 32);
    float inv = 1.0f / lr[nj];
    int rowb = q0 + nj * 16 + fg * 4;
#pragma unroll
    for (int nt = 0; nt < 8; ++nt) {
      int dcol = h * HD + nt * 16 + fl;
      Ob[(size_t)(rowb + 0) * D_ + dcol] = f2bf(o[nj][nt][0] * inv);
      Ob[(size_t)(rowb + 1) * D_ + dcol] = f2bf(o[nj][nt][1] * inv);
      Ob[(size_t)(rowb + 2) * D_ + dcol] = f2bf(o[nj][nt][2] * inv);
      Ob[(size_t)(rowb + 3) * D_ + dcol] = f2bf(o[nj][nt][3] * inv);
    }
  }
}

// ---------------- launch ----------------
extern "C" void kernel_launch(void* const* d_in, const int* in_sizes, int n_in,
                              void* d_out, int out_size, void* d_ws, size_t ws_size,
                              hipStream_t stream) {
  (void)in_sizes; (void)n_in; (void)out_size;
  const float* x    = (const float*)d_in[0];
  const int* seqln  = (const int*)d_in[1];
  const int* gsz    = (const int*)d_in[2];
  const float* fcos = (const float*)d_in[3];
  const float* fsin = (const float*)d_in[4];
  const float* Wq = (const float*)d_in[5];
  const float* bq = (const float*)d_in[6];
  const float* Wk = (const float*)d_in[7];
  const float* bk = (const float*)d_in[8];
  const float* Wv = (const float*)d_in[9];
  const float* bv = (const float*)d_in[10];
  const float* Wo = (const float*)d_in[11];
  const float* bo = (const float*)d_in[12];
  const float* gq = (const float*)d_in[13];
  const float* gk = (const float*)d_in[14];

  char* ws = (char*)d_ws;
  size_t LD2  = (size_t)L_ * D_ * 2;     // 12.58 MB
  size_t WD2  = (size_t)D_ * D_ * 2;     // 4.72 MB
  size_t LD4  = (size_t)L_ * D_ * 4;     // 25.2 MB
  size_t LNH4 = (size_t)L_ * NH * 4;     // 196 KB
  unsigned short* xb  = (unsigned short*)(ws);            // x bf16; later attn out
  unsigned short* qb  = (unsigned short*)(ws + LD2);
  unsigned short* kb  = (unsigned short*)(ws + 2 * LD2);
  unsigned short* vtb = (unsigned short*)(ws + 3 * LD2);  // V, K-tiled transposed
  unsigned short* wb0 = (unsigned short*)(ws + 4 * LD2);
  unsigned short* wb1 = (unsigned short*)(ws + 4 * LD2 + WD2);
  unsigned short* wb2 = (unsigned short*)(ws + 4 * LD2 + 2 * WD2);
  unsigned short* wb3 = (unsigned short*)(ws + 4 * LD2 + 3 * WD2);
  unsigned short* ab  = xb;

  int nx8 = L_ * D_ / 8, nw8 = D_ * D_ / 8;
  dim3 gg(D_ / 128, L_ / 128);

  size_t base  = 4 * LD2 + 4 * WD2;
  size_t need2 = base + LD4 + 2 * LNH4;
  size_t need4 = base + 3 * LD4 + 4 * LNH4;
  bool fusedw = ws_size >= base;

  if (fusedw) {
    int ntot = nx8 + 4 * nw8;   // exact multiple of 256
    cvt_all<<<ntot / 256, 256, 0, stream>>>(x, Wq, Wk, Wv, Wo, xb, wb0, wb1, wb2, wb3);
    gemm_qkv<<<dim3(3 * D_ / 128, L_ / 128), 256, 0, stream>>>(
        xb, wb0, wb1, wb2, bq, bk, bv, qb, kb, vtb);
  } else {
    cvt_f32_bf16<<<(nx8 + 255) / 256, 256, 0, stream>>>(x, xb, nx8);
    cvt_f32_bf16<<<(nw8 + 255) / 256, 256, 0, stream>>>(Wq, wb0, nw8);
    gemm_bt<1><<<gg, 256, 0, stream>>>(xb, wb0, bq, qb, L_, D_, D_);
    cvt_f32_bf16<<<(nw8 + 255) / 256, 256, 0, stream>>>(Wk, wb0, nw8);
    gemm_bt<1><<<gg, 256, 0, stream>>>(xb, wb0, bk, kb, L_, D_, D_);
    cvt_f32_bf16<<<(nw8 + 255) / 256, 256, 0, stream>>>(Wv, wb0, nw8);
    gemm_bt<2><<<gg, 256, 0, stream>>>(xb, wb0, bv, vtb, L_, D_, D_);
  }

  rmsrope<<<dim3(L_, 2), 256, 0, stream>>>(qb, kb, gq, gk, fcos, fsin, gsz);

  if (fusedw && ws_size >= need4) {
    float* Opd = (float*)d_out;                 // scratch; overwritten by Wo GEMM
    float* Opw = (float*)(ws + base);
    float* lp  = (float*)(ws + base + 3 * LD4);
    attnS<4><<<dim3(4 * 384), 256, 0, stream>>>(qb, kb, vtb, Opd, Opw, lp, seqln);
    attn_combine<4><<<dim3(L_ * D_ / 8 / 256), 256, 0, stream>>>(Opd, Opw, lp, ab);
  } else if (fusedw && ws_size >= need2) {
    float* Opd = (float*)d_out;
    float* Opw = (float*)(ws + base);
    float* lp  = (float*)(ws + base + LD4);
    attnS<2><<<dim3(2 * 384), 256, 0, stream>>>(qb, kb, vtb, Opd, Opw, lp, seqln);
    attn_combine<2><<<dim3(L_ * D_ / 8 / 256), 256, 0, stream>>>(Opd, Opw, lp, ab);
  } else {
    attn5<<<dim3(384), 256, 0, stream>>>(qb, kb, vtb, ab, seqln);
  }

  if (fusedw) {
    gemm_bt<0><<<gg, 256, 0, stream>>>(ab, wb3, bo, d_out, L_, D_, D_);
  } else {
    cvt_f32_bf16<<<(nw8 + 255) / 256, 256, 0, stream>>>(Wo, wb0, nw8);
    gemm_bt<0><<<gg, 256, 0, stream>>>(ab, wb0, bo, d_out, L_, D_, D_);
  }
}